// Round 1
// baseline (156.155 us; speedup 1.0000x reference)
//
#include <hip/hip_runtime.h>

#define NANCH 131072
#define NMAX  64
#define NBATCH 16

// ---------------------------------------------------------------------------
// ws layout:
//   [0, 8KB)        : unsigned long long cells[NBATCH*NMAX]  (packed argmax)
//   [8KB, 8KB+64KB) : double partials[8192]                  (block sums)
// ---------------------------------------------------------------------------

__global__ __launch_bounds__(256) void k_init(unsigned long long* cells) {
    int i = blockIdx.x * 256 + threadIdx.x;
    if (i < NBATCH * NMAX) cells[i] = 0ull;
}

// Per-GT argmax over all anchors. Packed (iou_bits<<32)|(0x7FFFFFFF-idx):
// iou >= 0 so float bits are unsigned-monotonic; ties -> larger low word ->
// smaller anchor index == JAX argmax first-occurrence semantics.
__global__ __launch_bounds__(256) void k_argmax(
    const float* __restrict__ anchors,   // [A,4] xyxy
    const float* __restrict__ gt,        // [B,NMAX,4] xywh
    const int*   __restrict__ nobj,      // [B]
    unsigned long long* __restrict__ cells)
{
    const int CHUNKS = NANCH / 2048;     // 64 blocks per batch, 2048 anchors each
    int b     = blockIdx.x / CHUNKS;
    int chunk = blockIdx.x % CHUNKS;
    int tid   = threadIdx.x;
    int n_obj = nobj[b];

    __shared__ float4 sbox[NMAX];
    __shared__ float  sarea[NMAX];
    if (tid < NMAX) {
        float4 g = reinterpret_cast<const float4*>(gt)[b * NMAX + tid];
        float x2 = g.x + g.z, y2 = g.y + g.w;
        sbox[tid]  = make_float4(g.x, g.y, x2, y2);
        sarea[tid] = (x2 - g.x) * (y2 - g.y);
    }
    __syncthreads();

    // 8 anchors per thread, lane-consecutive float4 loads (coalesced)
    float ax1[8], ay1[8], ax2[8], ay2[8], aar[8];
    int abase = chunk * 2048 + tid;
    #pragma unroll
    for (int k = 0; k < 8; ++k) {
        float4 v = reinterpret_cast<const float4*>(anchors)[abase + k * 256];
        ax1[k] = v.x; ay1[k] = v.y; ax2[k] = v.z; ay2[k] = v.w;
        aar[k] = (v.z - v.x) * (v.w - v.y);
    }

    for (int n = 0; n < n_obj; ++n) {
        float4 g  = sbox[n];
        float  ab = sarea[n];
        float best = -1.0f;
        int   bi   = 0;
        #pragma unroll
        for (int k = 0; k < 8; ++k) {
            float lx = fmaxf(ax1[k], g.x);
            float ly = fmaxf(ay1[k], g.y);
            float rx = fminf(ax2[k], g.z);
            float ry = fminf(ay2[k], g.w);
            float w  = fmaxf(rx - lx, 0.0f);
            float h  = fmaxf(ry - ly, 0.0f);
            float inter = w * h;
            float denom = aar[k] + ab - inter;        // > 0 always
            float iou   = inter * __builtin_amdgcn_rcpf(denom); // order only
            if (iou > best) { best = iou; bi = abase + k * 256; }
        }
        unsigned long long pk =
            ((unsigned long long)__float_as_uint(best) << 32)
          | (unsigned long long)(0x7FFFFFFFu - (unsigned)bi);
        #pragma unroll
        for (int off = 32; off; off >>= 1) {
            unsigned long long o = __shfl_xor(pk, off, 64);
            if (o > pk) pk = o;
        }
        if ((tid & 63) == 0) atomicMax(&cells[b * NMAX + n], pk);
    }
}

// Per-anchor match count + focal loss, block partial sums (deterministic).
__global__ __launch_bounds__(256) void k_loss(
    const float* __restrict__ thr_p,
    const float* __restrict__ classes,   // [B,A,2]
    const float* __restrict__ anchors,   // [A,4]
    const float* __restrict__ gt,        // [B,NMAX,4] xywh
    const int*   __restrict__ nobj,
    const unsigned long long* __restrict__ cells,
    double* __restrict__ partials)
{
    const int BPB = NANCH / 256;         // 512 blocks per batch
    int b   = blockIdx.x / BPB;
    int tid = threadIdx.x;
    int a   = (blockIdx.x % BPB) * 256 + tid;
    float thr = *thr_p;
    int n_obj = nobj[b];

    __shared__ float4 sbox[NMAX];
    __shared__ float  sarea[NMAX];
    __shared__ int    sbest[NMAX];
    if (tid < NMAX) {
        float4 g = reinterpret_cast<const float4*>(gt)[b * NMAX + tid];
        float x2 = g.x + g.z, y2 = g.y + g.w;
        sbox[tid]  = make_float4(g.x, g.y, x2, y2);
        sarea[tid] = (x2 - g.x) * (y2 - g.y);
        sbest[tid] = (int)(0x7FFFFFFFu -
                     (unsigned)(cells[b * NMAX + tid] & 0xFFFFFFFFull));
    }
    __syncthreads();

    float4 av  = reinterpret_cast<const float4*>(anchors)[a];
    float  aar = (av.z - av.x) * (av.w - av.y);
    float  t1  = 1.0f + thr;

    int count = 0;
    for (int n = 0; n < n_obj; ++n) {
        float4 g = sbox[n];
        float lx = fmaxf(av.x, g.x);
        float ly = fmaxf(av.y, g.y);
        float rx = fminf(av.z, g.z);
        float ry = fminf(av.w, g.w);
        float w  = fmaxf(rx - lx, 0.0f);
        float h  = fmaxf(ry - ly, 0.0f);
        float inter = w * h;
        float sa = aar + sarea[n];
        // iou > thr  <=>  inter*(1+thr) > thr*(sumarea)   (denom > 0)
        bool pos = (inter * t1 > thr * sa) || (a == sbest[n]);
        count += pos ? 1 : 0;
    }

    float2 c = reinterpret_cast<const float2*>(classes)[(size_t)b * NANCH + a];
    float p  = (count > 0) ? c.y : c.x;
    float om = 1.0f - p;
    float focal   = -om * om * __logf(p);
    float contrib = focal * (1.0f + 10.0f * (float)count);

    double v = (double)contrib;
    #pragma unroll
    for (int off = 32; off; off >>= 1) v += __shfl_xor(v, off, 64);
    __shared__ double sw[4];
    if ((tid & 63) == 0) sw[tid >> 6] = v;
    __syncthreads();
    if (tid == 0) partials[blockIdx.x] = sw[0] + sw[1] + sw[2] + sw[3];
}

__global__ __launch_bounds__(256) void k_final(
    const double* __restrict__ partials, int np, float* __restrict__ out)
{
    int tid = threadIdx.x;
    double v = 0.0;
    for (int i = tid; i < np; i += 256) v += partials[i];
    #pragma unroll
    for (int off = 32; off; off >>= 1) v += __shfl_xor(v, off, 64);
    __shared__ double sw[4];
    if ((tid & 63) == 0) sw[tid >> 6] = v;
    __syncthreads();
    if (tid == 0) {
        double cls = (sw[0] + sw[1] + sw[2] + sw[3]) * (0.01 / 16.0);
        out[0] = (float)cls;   // total = class + coord(0)
        out[1] = (float)cls;
        out[2] = 0.0f;
    }
}

extern "C" void kernel_launch(void* const* d_in, const int* in_sizes, int n_in,
                              void* d_out, int out_size, void* d_ws, size_t ws_size,
                              hipStream_t stream) {
    const float* thr     = (const float*)d_in[0];
    const float* classes = (const float*)d_in[1];
    const float* anchors = (const float*)d_in[2];
    const float* gt      = (const float*)d_in[3];
    const int*   nobj    = (const int*)d_in[4];
    float* out = (float*)d_out;

    unsigned long long* cells = (unsigned long long*)d_ws;
    double* partials = (double*)((char*)d_ws + NBATCH * NMAX * sizeof(unsigned long long));

    k_init<<<(NBATCH * NMAX + 255) / 256, 256, 0, stream>>>(cells);
    k_argmax<<<NBATCH * (NANCH / 2048), 256, 0, stream>>>(anchors, gt, nobj, cells);
    k_loss<<<NBATCH * (NANCH / 256), 256, 0, stream>>>(thr, classes, anchors, gt, nobj,
                                                       cells, partials);
    k_final<<<1, 256, 0, stream>>>(partials, NBATCH * (NANCH / 256), out);
}

// Round 2
// 116.268 us; speedup vs baseline: 1.3431x; 1.3431x over previous
//
#include <hip/hip_runtime.h>

#define NANCH 131072
#define NMAX  64
#define NBATCH 16

// ---------------------------------------------------------------------------
// ws layout:
//   [0, 8KB)         : unsigned long long cells[NBATCH*NMAX]  (packed argmax)
//   [8KB, 8KB+8KB)   : double partials[1024]                  (block sums)
// ---------------------------------------------------------------------------

__global__ __launch_bounds__(256) void k_init(unsigned long long* cells) {
    int i = blockIdx.x * 256 + threadIdx.x;
    if (i < NBATCH * NMAX) cells[i] = 0ull;
}

// Per-GT argmax over anchors, parallelized over (batch, gt-chunk, anchor-chunk)
// for load balance. Packed (iou_bits<<32)|(0x7FFFFFFF-idx): iou >= 0 so float
// bits are unsigned-monotonic; ties -> larger low word -> smaller anchor index
// == JAX argmax first-occurrence semantics.
#define GTC 8                      // GTs per block
#define APT 16                     // anchors per thread
#define ACH (256 * APT)            // 4096 anchors per block
#define NCH_A (NANCH / ACH)        // 32 anchor chunks
#define NCH_G (NMAX / GTC)         // 8 gt chunks

__global__ __launch_bounds__(256) void k_argmax(
    const float* __restrict__ anchors,   // [A,4] xyxy
    const float* __restrict__ gt,        // [B,NMAX,4] xywh
    const int*   __restrict__ nobj,      // [B]
    unsigned long long* __restrict__ cells)
{
    int b   = blockIdx.x / (NCH_G * NCH_A);
    int r   = blockIdx.x % (NCH_G * NCH_A);
    int g0  = (r / NCH_A) * GTC;
    int ach = r % NCH_A;
    int n_obj = nobj[b];
    if (g0 >= n_obj) return;             // early exit -> balance
    int n_end = min(GTC, n_obj - g0);

    int tid = threadIdx.x;
    __shared__ float4 sbox[GTC];
    __shared__ float  sarea[GTC];
    if (tid < GTC) {
        float4 g = reinterpret_cast<const float4*>(gt)[b * NMAX + g0 + tid];
        float x2 = g.x + g.z, y2 = g.y + g.w;
        sbox[tid]  = make_float4(g.x, g.y, x2, y2);
        sarea[tid] = (x2 - g.x) * (y2 - g.y);
    }
    __syncthreads();

    float ax1[APT], ay1[APT], ax2[APT], ay2[APT], aar[APT];
    int abase = ach * ACH + tid;
    #pragma unroll
    for (int k = 0; k < APT; ++k) {
        float4 v = reinterpret_cast<const float4*>(anchors)[abase + k * 256];
        ax1[k] = v.x; ay1[k] = v.y; ax2[k] = v.z; ay2[k] = v.w;
        aar[k] = (v.z - v.x) * (v.w - v.y);
    }

    for (int n = 0; n < n_end; ++n) {
        float4 g  = sbox[n];
        float  ab = sarea[n];
        float best = -1.0f;
        int   bi   = 0;
        #pragma unroll
        for (int k = 0; k < APT; ++k) {
            float lx = fmaxf(ax1[k], g.x);
            float ly = fmaxf(ay1[k], g.y);
            float rx = fminf(ax2[k], g.z);
            float ry = fminf(ay2[k], g.w);
            float w  = fmaxf(rx - lx, 0.0f);
            float h  = fmaxf(ry - ly, 0.0f);
            float inter = w * h;
            float denom = aar[k] + ab - inter;                  // > 0 always
            float iou   = inter * __builtin_amdgcn_rcpf(denom); // order only
            if (iou > best) { best = iou; bi = abase + k * 256; }
        }
        unsigned long long pk =
            ((unsigned long long)__float_as_uint(best) << 32)
          | (unsigned long long)(0x7FFFFFFFu - (unsigned)bi);
        #pragma unroll
        for (int off = 32; off; off >>= 1) {
            unsigned long long o = __shfl_xor(pk, off, 64);
            if (o > pk) pk = o;
        }
        if ((tid & 63) == 0) atomicMax(&cells[b * NMAX + g0 + n], pk);
    }
}

// Per-anchor match count + focal loss. Each thread owns ONE anchor and loops
// over 8 batches (2 interleaved groups) -> every block does ~sum(n_obj)/2
// inner iterations: near-perfect balance regardless of per-batch n_obj.
#define NGRP 2
#define BPG  (NBATCH / NGRP)       // 8 batches per group

__global__ __launch_bounds__(256) void k_loss(
    const float* __restrict__ thr_p,
    const float* __restrict__ classes,   // [B,A,2]
    const float* __restrict__ anchors,   // [A,4]
    const float* __restrict__ gt,        // [B,NMAX,4] xywh
    const int*   __restrict__ nobj,
    const unsigned long long* __restrict__ cells,
    double* __restrict__ partials)
{
    const int BPB = NANCH / 256;         // 512 anchor chunks
    int grp  = blockIdx.x / BPB;
    int tid  = threadIdx.x;
    int a    = (blockIdx.x % BPB) * 256 + tid;
    float thr = *thr_p;

    __shared__ float4 sbox[BPG * NMAX];  // xyxy
    __shared__ float  stsa[BPG * NMAX];  // thr * gt_area
    __shared__ int    sbest[BPG * NMAX];
    __shared__ int    snobj[BPG];
    for (int j = tid; j < BPG * NMAX; j += 256) {
        int bb = j >> 6, n = j & 63;
        int b  = grp + NGRP * bb;
        float4 g = reinterpret_cast<const float4*>(gt)[b * NMAX + n];
        float x2 = g.x + g.z, y2 = g.y + g.w;
        sbox[j] = make_float4(g.x, g.y, x2, y2);
        stsa[j] = thr * ((x2 - g.x) * (y2 - g.y));
        sbest[j] = (int)(0x7FFFFFFFu -
                   (unsigned)(cells[b * NMAX + n] & 0xFFFFFFFFull));
    }
    if (tid < BPG) snobj[tid] = nobj[grp + NGRP * tid];
    __syncthreads();

    float4 av  = reinterpret_cast<const float4*>(anchors)[a];
    float  aar = (av.z - av.x) * (av.w - av.y);
    float  t1  = 1.0f + thr;
    float  ta  = thr * aar;

    double acc = 0.0;
    #pragma unroll
    for (int bb = 0; bb < BPG; ++bb) {
        int b  = grp + NGRP * bb;
        int no = snobj[bb];
        int count = 0;
        int base  = bb * NMAX;
        for (int n = 0; n < no; ++n) {
            float4 g = sbox[base + n];
            float lx = fmaxf(av.x, g.x);
            float ly = fmaxf(av.y, g.y);
            float rx = fminf(av.z, g.z);
            float ry = fminf(av.w, g.w);
            float w  = fmaxf(rx - lx, 0.0f);
            float h  = fmaxf(ry - ly, 0.0f);
            float inter = w * h;
            // iou > thr  <=>  inter*(1+thr) > thr*(areaA+areaB)   (denom > 0)
            bool pos = (inter * t1 > ta + stsa[base + n]) || (a == sbest[base + n]);
            count += pos ? 1 : 0;
        }
        float2 c = reinterpret_cast<const float2*>(classes)[(size_t)b * NANCH + a];
        float p  = (count > 0) ? c.y : c.x;
        float om = 1.0f - p;
        float focal = -om * om * __logf(p);
        acc += (double)(focal * (1.0f + 10.0f * (float)count));
    }

    #pragma unroll
    for (int off = 32; off; off >>= 1) acc += __shfl_xor(acc, off, 64);
    __shared__ double sw[4];
    if ((tid & 63) == 0) sw[tid >> 6] = acc;
    __syncthreads();
    if (tid == 0) partials[blockIdx.x] = sw[0] + sw[1] + sw[2] + sw[3];
}

__global__ __launch_bounds__(256) void k_final(
    const double* __restrict__ partials, int np, float* __restrict__ out)
{
    int tid = threadIdx.x;
    double v = 0.0;
    for (int i = tid; i < np; i += 256) v += partials[i];
    #pragma unroll
    for (int off = 32; off; off >>= 1) v += __shfl_xor(v, off, 64);
    __shared__ double sw[4];
    if ((tid & 63) == 0) sw[tid >> 6] = v;
    __syncthreads();
    if (tid == 0) {
        double cls = (sw[0] + sw[1] + sw[2] + sw[3]) * (0.01 / 16.0);
        out[0] = (float)cls;   // total = class + coord(0)
        out[1] = (float)cls;
        out[2] = 0.0f;
    }
}

extern "C" void kernel_launch(void* const* d_in, const int* in_sizes, int n_in,
                              void* d_out, int out_size, void* d_ws, size_t ws_size,
                              hipStream_t stream) {
    const float* thr     = (const float*)d_in[0];
    const float* classes = (const float*)d_in[1];
    const float* anchors = (const float*)d_in[2];
    const float* gt      = (const float*)d_in[3];
    const int*   nobj    = (const int*)d_in[4];
    float* out = (float*)d_out;

    unsigned long long* cells = (unsigned long long*)d_ws;
    double* partials = (double*)((char*)d_ws + NBATCH * NMAX * sizeof(unsigned long long));

    k_init<<<(NBATCH * NMAX + 255) / 256, 256, 0, stream>>>(cells);
    k_argmax<<<NBATCH * NCH_G * NCH_A, 256, 0, stream>>>(anchors, gt, nobj, cells);
    k_loss<<<NGRP * (NANCH / 256), 256, 0, stream>>>(thr, classes, anchors, gt, nobj,
                                                     cells, partials);
    k_final<<<1, 256, 0, stream>>>(partials, NGRP * (NANCH / 256), out);
}

// Round 3
// 97.597 us; speedup vs baseline: 1.6000x; 1.1913x over previous
//
#include <hip/hip_runtime.h>

#define NANCH   131072
#define NMAX    64
#define NBATCH  16
#define THREADS 256

// argmax-role geometry
#define GTC   8                        // GTs per block
#define APT   16                       // anchors per thread
#define ACH   (THREADS * APT)          // 4096 anchors per block
#define NCH_A (NANCH / ACH)            // 32 anchor chunks
#define NCH_G (NMAX / GTC)             // 8 gt chunks
#define NB_CNT (NANCH / THREADS)       // 512 count-role blocks
#define NB_ARG (NBATCH * NCH_G * NCH_A)// 4096 argmax-role blocks
#define NPART  (NB_CNT + NBATCH)       // 528 partial sums

// ---------------------------------------------------------------------------
// ws layout:
//   [0, 8KB)        : unsigned long long cells[NBATCH*NMAX]  (packed argmax)
//   [8KB, 8KB+4.3K) : double partials[NPART]
// cells packed as (iou_bits<<32)|(0x7FFFFFFF-idx): iou>=0 so float bits are
// unsigned-monotonic; ties -> larger low word -> smaller anchor index == JAX
// argmax first-occurrence semantics.
// ---------------------------------------------------------------------------

__global__ __launch_bounds__(256) void k_phase1(
    const float* __restrict__ thr_p,
    const float* __restrict__ classes,   // [B,A,2]
    const float* __restrict__ anchors,   // [A,4] xyxy
    const float* __restrict__ gt,        // [B,NMAX,4] xywh
    const int*   __restrict__ nobj,      // [B]
    unsigned long long* __restrict__ cells,
    double* __restrict__ partials)
{
    int tid = threadIdx.x;

    if (blockIdx.x < NB_CNT) {
        // ============ count + focal role: 1 anchor/thread, all 16 batches ====
        float thr = *thr_p;
        int a = blockIdx.x * THREADS + tid;

        __shared__ float4 sbox[NBATCH * NMAX];   // xyxy
        __shared__ float  stsa[NBATCH * NMAX];   // thr * gt_area
        __shared__ int    snobj[NBATCH];
        for (int j = tid; j < NBATCH * NMAX; j += THREADS) {
            int b = j >> 6, n = j & 63;
            float4 g = reinterpret_cast<const float4*>(gt)[b * NMAX + n];
            float x2 = g.x + g.z, y2 = g.y + g.w;
            sbox[j] = make_float4(g.x, g.y, x2, y2);
            stsa[j] = thr * ((x2 - g.x) * (y2 - g.y));
        }
        if (tid < NBATCH) snobj[tid] = nobj[tid];
        __syncthreads();

        float4 av  = reinterpret_cast<const float4*>(anchors)[a];
        float  aar = (av.z - av.x) * (av.w - av.y);
        float  t1  = 1.0f + thr;
        float  ta  = thr * aar;

        double acc = 0.0;
        for (int b = 0; b < NBATCH; ++b) {
            int no   = snobj[b];
            int base = b * NMAX;
            int count = 0;
            #pragma unroll 4
            for (int n = 0; n < no; ++n) {
                float4 g = sbox[base + n];
                float lx = fmaxf(av.x, g.x);
                float ly = fmaxf(av.y, g.y);
                float rx = fminf(av.z, g.z);
                float ry = fminf(av.w, g.w);
                float w  = fmaxf(rx - lx, 0.0f);
                float h  = fmaxf(ry - ly, 0.0f);
                float inter = w * h;
                // iou > thr  <=>  inter*(1+thr) > thr*areaA + thr*areaB
                count += (inter * t1 > ta + stsa[base + n]) ? 1 : 0;
            }
            float2 c = reinterpret_cast<const float2*>(classes)[(size_t)b * NANCH + a];
            float p  = (count > 0) ? c.y : c.x;
            float om = 1.0f - p;
            float focal = -om * om * __logf(p);
            acc += (double)(focal * (1.0f + 10.0f * (float)count));
        }

        #pragma unroll
        for (int off = 32; off; off >>= 1) acc += __shfl_xor(acc, off, 64);
        __shared__ double sw[4];
        if ((tid & 63) == 0) sw[tid >> 6] = acc;
        __syncthreads();
        if (tid == 0) partials[blockIdx.x] = sw[0] + sw[1] + sw[2] + sw[3];

    } else {
        // ============ argmax role: (batch, gt-chunk, anchor-chunk) ==========
        int bid = blockIdx.x - NB_CNT;
        int b   = bid / (NCH_G * NCH_A);
        int r   = bid % (NCH_G * NCH_A);
        int g0  = (r / NCH_A) * GTC;
        int ach = r % NCH_A;
        int n_obj = nobj[b];
        if (g0 >= n_obj) return;
        int n_end = min(GTC, n_obj - g0);

        __shared__ float4 gsb[GTC];
        __shared__ float  gsa[GTC];
        if (tid < GTC) {
            float4 g = reinterpret_cast<const float4*>(gt)[b * NMAX + g0 + tid];
            float x2 = g.x + g.z, y2 = g.y + g.w;
            gsb[tid] = make_float4(g.x, g.y, x2, y2);
            gsa[tid] = (x2 - g.x) * (y2 - g.y);
        }
        __syncthreads();

        float gx1[GTC], gy1[GTC], gx2[GTC], gy2[GTC], gar[GTC];
        #pragma unroll
        for (int n = 0; n < GTC; ++n) {
            float4 g = gsb[n];
            gx1[n] = g.x; gy1[n] = g.y; gx2[n] = g.z; gy2[n] = g.w;
            gar[n] = gsa[n];
        }

        // running best per gt, cross-multiplication order (no rcp in loop):
        // iouA > iouB  <=>  interA*denB > interB*denA   (dens > 0)
        float bnum[GTC], bden[GTC]; int bix[GTC];
        #pragma unroll
        for (int n = 0; n < GTC; ++n) { bnum[n] = -1.0f; bden[n] = 1.0f; bix[n] = 0; }

        int abase = ach * ACH + tid;
        #pragma unroll
        for (int k = 0; k < APT; ++k) {
            int aidx = abase + k * THREADS;
            float4 v = reinterpret_cast<const float4*>(anchors)[aidx];
            float aar = (v.z - v.x) * (v.w - v.y);
            #pragma unroll
            for (int n = 0; n < GTC; ++n) {
                float lx = fmaxf(v.x, gx1[n]);
                float ly = fmaxf(v.y, gy1[n]);
                float rx = fminf(v.z, gx2[n]);
                float ry = fminf(v.w, gy2[n]);
                float w  = fmaxf(rx - lx, 0.0f);
                float h  = fmaxf(ry - ly, 0.0f);
                float inter = w * h;
                float den   = (aar + gar[n]) - inter;
                bool better = inter * bden[n] > bnum[n] * den;
                bnum[n] = better ? inter : bnum[n];
                bden[n] = better ? den   : bden[n];
                bix[n]  = better ? aidx  : bix[n];
            }
        }

        // finalize: one rcp per gt, pack, 8 interleaved butterfly chains
        unsigned long long pk[GTC];
        #pragma unroll
        for (int n = 0; n < GTC; ++n) {
            float iou = bnum[n] * __builtin_amdgcn_rcpf(bden[n]);  // order only
            pk[n] = ((unsigned long long)__float_as_uint(iou) << 32)
                  | (unsigned long long)(0x7FFFFFFFu - (unsigned)bix[n]);
        }
        #pragma unroll
        for (int off = 32; off; off >>= 1) {
            #pragma unroll
            for (int n = 0; n < GTC; ++n) {
                unsigned long long o = __shfl_xor(pk[n], off, 64);
                if (o > pk[n]) pk[n] = o;
            }
        }
        if ((tid & 63) == 0) {
            #pragma unroll
            for (int n = 0; n < GTC; ++n)
                if (n < n_end) atomicMax(&cells[b * NMAX + g0 + n], pk[n]);
        }
    }
}

// Sparse forced-positive correction: for each valid gt whose best anchor is
// not already above threshold, add (new contrib - old contrib) for that
// anchor. Expressions are bit-identical to the count role so the "old"
// contribution cancels exactly.
__global__ __launch_bounds__(64) void k_correct(
    const float* __restrict__ thr_p,
    const float* __restrict__ classes,
    const float* __restrict__ anchors,
    const float* __restrict__ gt,
    const int*   __restrict__ nobj,
    const unsigned long long* __restrict__ cells,
    double* __restrict__ partials)
{
    int b   = blockIdx.x;
    int tid = threadIdx.x;           // gt index n
    int n_obj = nobj[b];
    float thr = *thr_p;
    float t1  = 1.0f + thr;

    __shared__ float4 sbox[NMAX];
    __shared__ float  stsa[NMAX];
    {
        float4 g = reinterpret_cast<const float4*>(gt)[b * NMAX + tid];
        float x2 = g.x + g.z, y2 = g.y + g.w;
        sbox[tid] = make_float4(g.x, g.y, x2, y2);
        stsa[tid] = thr * ((x2 - g.x) * (y2 - g.y));
    }
    __syncthreads();

    bool valid = tid < n_obj;
    int  bi = -1;
    bool need = false;
    float4 av = make_float4(0.f, 0.f, 0.f, 0.f);
    float ta = 0.f;
    if (valid) {
        unsigned long long pkv = cells[b * NMAX + tid];
        bi = (int)(0x7FFFFFFFu - (unsigned)(pkv & 0xFFFFFFFFull));
        av = reinterpret_cast<const float4*>(anchors)[bi];
        float aar = (av.z - av.x) * (av.w - av.y);
        ta = thr * aar;
        float4 g = sbox[tid];
        float lx = fmaxf(av.x, g.x);
        float ly = fmaxf(av.y, g.y);
        float rx = fminf(av.z, g.z);
        float ry = fminf(av.w, g.w);
        float w  = fmaxf(rx - lx, 0.0f);
        float h  = fmaxf(ry - ly, 0.0f);
        float inter = w * h;
        bool pos = inter * t1 > ta + stsa[tid];
        need = !pos;                 // forced adds a new mask bit only if !pos
    }

    __shared__ int sidx[NMAX];
    sidx[tid] = need ? bi : -1;
    __syncthreads();

    double delta = 0.0;
    if (need) {
        bool first = true;
        int  extra = 0;
        for (int m = 0; m < NMAX; ++m) {
            if (sidx[m] == bi) { if (m < tid) first = false; extra += 1; }
        }
        if (first) {
            int count = 0;
            for (int n = 0; n < n_obj; ++n) {
                float4 g = sbox[n];
                float lx = fmaxf(av.x, g.x);
                float ly = fmaxf(av.y, g.y);
                float rx = fminf(av.z, g.z);
                float ry = fminf(av.w, g.w);
                float w  = fmaxf(rx - lx, 0.0f);
                float h  = fmaxf(ry - ly, 0.0f);
                float inter = w * h;
                count += (inter * t1 > ta + stsa[n]) ? 1 : 0;
            }
            float2 c = reinterpret_cast<const float2*>(classes)[(size_t)b * NANCH + bi];
            float po = (count > 0) ? c.y : c.x;
            float oo = 1.0f - po;
            float fo = -oo * oo * __logf(po);
            float oldc = fo * (1.0f + 10.0f * (float)count);
            int cn = count + extra;
            float pn = (cn > 0) ? c.y : c.x;
            float on = 1.0f - pn;
            float fn = -on * on * __logf(pn);
            float newc = fn * (1.0f + 10.0f * (float)cn);
            delta = (double)newc - (double)oldc;
        }
    }
    #pragma unroll
    for (int off = 32; off; off >>= 1) delta += __shfl_xor(delta, off, 64);
    if (tid == 0) partials[NB_CNT + b] = delta;
}

__global__ __launch_bounds__(256) void k_final(
    const double* __restrict__ partials, float* __restrict__ out)
{
    int tid = threadIdx.x;
    double v = 0.0;
    for (int i = tid; i < NPART; i += 256) v += partials[i];
    #pragma unroll
    for (int off = 32; off; off >>= 1) v += __shfl_xor(v, off, 64);
    __shared__ double sw[4];
    if ((tid & 63) == 0) sw[tid >> 6] = v;
    __syncthreads();
    if (tid == 0) {
        double cls = (sw[0] + sw[1] + sw[2] + sw[3]) * (0.01 / 16.0);
        out[0] = (float)cls;   // total = class + coord(0)
        out[1] = (float)cls;
        out[2] = 0.0f;
    }
}

extern "C" void kernel_launch(void* const* d_in, const int* in_sizes, int n_in,
                              void* d_out, int out_size, void* d_ws, size_t ws_size,
                              hipStream_t stream) {
    const float* thr     = (const float*)d_in[0];
    const float* classes = (const float*)d_in[1];
    const float* anchors = (const float*)d_in[2];
    const float* gt      = (const float*)d_in[3];
    const int*   nobj    = (const int*)d_in[4];
    float* out = (float*)d_out;

    unsigned long long* cells = (unsigned long long*)d_ws;
    double* partials = (double*)((char*)d_ws + NBATCH * NMAX * sizeof(unsigned long long));

    hipMemsetAsync(cells, 0, NBATCH * NMAX * sizeof(unsigned long long), stream);
    k_phase1<<<NB_CNT + NB_ARG, THREADS, 0, stream>>>(thr, classes, anchors, gt, nobj,
                                                      cells, partials);
    k_correct<<<NBATCH, 64, 0, stream>>>(thr, classes, anchors, gt, nobj, cells, partials);
    k_final<<<1, 256, 0, stream>>>(partials, out);
}

// Round 4
// 91.286 us; speedup vs baseline: 1.7106x; 1.0691x over previous
//
#include <hip/hip_runtime.h>

#define NANCH   131072
#define NMAX    64
#define NBATCH  16
#define THREADS 256
#define APT     4                       // anchors per thread
#define ACH     (THREADS * APT)         // 1024 anchors per block
#define NCHUNK  (NANCH / ACH)           // 128 anchor chunks
#define NPAIR   (NBATCH / 2)            // 8 batch pairs
#define NBLK    (NCHUNK * NPAIR)        // 1024 phase blocks
#define GTG     8                       // gt group size

// ---------------------------------------------------------------------------
// ws layout:
//   [0, 8KB)           u64 cells[NBATCH*NMAX]   packed per-gt argmax
//   [8KB, 8KB+64B)     int pairs[16]            batch pairing (balance)
//   [8256, 8256+8KB)   double partials[NBLK]
// cells packed as (iou_bits<<32)|(0x7FFFFFFF-idx): iou>=0 so float bits are
// unsigned-monotonic; ties -> larger low word -> smaller anchor index == JAX
// argmax first-occurrence semantics.
// ---------------------------------------------------------------------------

__global__ __launch_bounds__(64) void k_setup(
    const int* __restrict__ nobj, unsigned long long* __restrict__ cells,
    int* __restrict__ pairs)
{
    int tid = threadIdx.x;
    for (int i = tid; i < NBATCH * NMAX; i += 64) cells[i] = 0ull;
    if (tid == 0) {
        int idx[NBATCH], key[NBATCH];
        for (int i = 0; i < NBATCH; ++i) { idx[i] = i; key[i] = nobj[i]; }
        for (int i = 1; i < NBATCH; ++i) {            // stable insertion, desc
            int kj = key[i], ij = idx[i], j = i - 1;
            while (j >= 0 && key[j] < kj) { key[j+1]=key[j]; idx[j+1]=idx[j]; --j; }
            key[j+1] = kj; idx[j+1] = ij;
        }
        for (int p = 0; p < NPAIR; ++p) {             // big + small -> equal sums
            pairs[2*p]   = idx[p];
            pairs[2*p+1] = idx[NBATCH-1-p];
        }
    }
}

// Single pass: each IoU computed ONCE, feeding both the threshold count
// (focal loss) and the per-gt argmax (cross-multiplied, no division in loop).
__global__ __launch_bounds__(THREADS) void k_phase(
    const float* __restrict__ thr_p,
    const float* __restrict__ classes,   // [B,A,2]
    const float* __restrict__ anchors,   // [A,4] xyxy
    const float* __restrict__ gt,        // [B,NMAX,4] xywh
    const int*   __restrict__ nobj,
    const int*   __restrict__ pairs,
    unsigned long long* __restrict__ cells,
    double* __restrict__ partials)
{
    int chunk = blockIdx.x / NPAIR;
    int pr    = blockIdx.x % NPAIR;
    int tid   = threadIdx.x;
    float thr = *thr_p;
    float t1  = 1.0f + thr;
    int b0 = pairs[2*pr], b1 = pairs[2*pr+1];

    __shared__ float4 sbox[2*NMAX];      // xyxy (degenerate-padded)
    __shared__ float  sgar[2*NMAX];      // gt area
    __shared__ float  stsg[2*NMAX];      // thr * gt area
    __shared__ int    sno[2];
    __shared__ unsigned long long spk[4][GTG];
    __shared__ double sw[4];

    for (int j = tid; j < 2*NMAX; j += THREADS) {
        int s = j >> 6, n = j & 63;
        int b = s ? b1 : b0;
        int no = nobj[b];
        float4 g = reinterpret_cast<const float4*>(gt)[b*NMAX + n];
        float x2 = g.x + g.z, y2 = g.y + g.w;
        float4 box = make_float4(g.x, g.y, x2, y2);
        float  ar  = (x2 - g.x) * (y2 - g.y);
        if (n >= no) { box = make_float4(4.f,4.f,4.f,4.f); ar = 0.f; } // pad: inter=0
        sbox[j] = box; sgar[j] = ar; stsg[j] = thr * ar;
    }
    if (tid < 2) sno[tid] = nobj[tid ? b1 : b0];
    __syncthreads();

    float ax1[APT], ay1[APT], ax2[APT], ay2[APT], aar[APT], ta[APT];
    int abase = chunk * ACH + tid;
    #pragma unroll
    for (int k = 0; k < APT; ++k) {
        float4 v = reinterpret_cast<const float4*>(anchors)[abase + k*THREADS];
        ax1[k]=v.x; ay1[k]=v.y; ax2[k]=v.z; ay2[k]=v.w;
        aar[k] = (v.z - v.x) * (v.w - v.y);
        ta[k]  = thr * aar[k];
    }

    int wv = tid >> 6, ln = tid & 63;
    double acc = 0.0;

    for (int s = 0; s < 2; ++s) {
        int b    = s ? b1 : b0;
        int no   = sno[s];
        int base = s * NMAX;
        int cnt[APT] = {0,0,0,0};

        for (int g0 = 0; g0 < no; g0 += GTG) {
            float bn[GTG], bd[GTG]; int bx[GTG];
            #pragma unroll
            for (int n = 0; n < GTG; ++n) { bn[n] = -1.f; bd[n] = 1.f; bx[n] = 0; }

            #pragma unroll
            for (int n = 0; n < GTG; ++n) {            // n outer: gt regs short-lived
                float4 g  = sbox[base + g0 + n];
                float gar = sgar[base + g0 + n];
                float tsg = stsg[base + g0 + n];
                #pragma unroll
                for (int k = 0; k < APT; ++k) {
                    float lx = fmaxf(ax1[k], g.x);
                    float ly = fmaxf(ay1[k], g.y);
                    float rx = fminf(ax2[k], g.z);
                    float ry = fminf(ay2[k], g.w);
                    float w  = fmaxf(rx - lx, 0.f);
                    float h  = fmaxf(ry - ly, 0.f);
                    float inter = w * h;
                    float den   = (aar[k] + gar) - inter;   // > 0 (real gt)
                    // iou > thr  <=>  inter*(1+thr) > thr*areaA + thr*areaB
                    cnt[k] += (inter * t1 > ta[k] + tsg) ? 1 : 0;
                    // iouA > iouBest <=> interA*bd > bn*denA  (both dens > 0)
                    bool better = inter * bd[n] > bn[n] * den;
                    bn[n] = better ? inter : bn[n];
                    bd[n] = better ? den   : bd[n];
                    bx[n] = better ? (abase + k*THREADS) : bx[n];
                }
            }

            unsigned long long pk[GTG];
            #pragma unroll
            for (int n = 0; n < GTG; ++n) {
                float iou = bn[n] * __builtin_amdgcn_rcpf(bd[n]);  // order only
                pk[n] = ((unsigned long long)__float_as_uint(iou) << 32)
                      | (unsigned long long)(0x7FFFFFFFu - (unsigned)bx[n]);
            }
            #pragma unroll
            for (int off = 32; off; off >>= 1) {       // 8 interleaved chains
                #pragma unroll
                for (int n = 0; n < GTG; ++n) {
                    unsigned long long o = __shfl_xor(pk[n], off, 64);
                    if (o > pk[n]) pk[n] = o;
                }
            }
            if (ln == 0) {
                #pragma unroll
                for (int n = 0; n < GTG; ++n) spk[wv][n] = pk[n];
            }
            __syncthreads();
            if (tid < GTG && g0 + tid < no) {          // one atomic per (block,gt)
                unsigned long long m0 = spk[0][tid] > spk[1][tid] ? spk[0][tid] : spk[1][tid];
                unsigned long long m1 = spk[2][tid] > spk[3][tid] ? spk[2][tid] : spk[3][tid];
                unsigned long long m  = m0 > m1 ? m0 : m1;
                atomicMax(&cells[b*NMAX + g0 + tid], m);
            }
            __syncthreads();
        }

        const float2* cp = reinterpret_cast<const float2*>(classes) + (size_t)b * NANCH;
        #pragma unroll
        for (int k = 0; k < APT; ++k) {
            float2 c = cp[abase + k*THREADS];
            float p  = (cnt[k] > 0) ? c.y : c.x;
            float om = 1.0f - p;
            float focal = -om * om * __logf(p);
            acc += (double)(focal * (1.0f + 10.0f * (float)cnt[k]));
        }
    }

    #pragma unroll
    for (int off = 32; off; off >>= 1) acc += __shfl_xor(acc, off, 64);
    if (ln == 0) sw[wv] = acc;
    __syncthreads();
    if (tid == 0) partials[blockIdx.x] = sw[0] + sw[1] + sw[2] + sw[3];
}

// One block, 1024 threads: sparse forced-positive correction (batch = tid>>6)
// + final reduction of all partials. Expressions bit-identical to k_phase so
// the "old" contribution cancels exactly.
__global__ __launch_bounds__(1024) void k_tail(
    const float* __restrict__ thr_p,
    const float* __restrict__ classes,
    const float* __restrict__ anchors,
    const float* __restrict__ gt,
    const int*   __restrict__ nobj,
    const unsigned long long* __restrict__ cells,
    const double* __restrict__ partials,
    float* __restrict__ out)
{
    int tid = threadIdx.x;
    int b = tid >> 6, n = tid & 63;
    float thr = *thr_p;
    float t1  = 1.0f + thr;

    __shared__ float4 sbox[NBATCH*NMAX];
    __shared__ float  stsa[NBATCH*NMAX];
    __shared__ int    sidx[NBATCH*NMAX];
    __shared__ double sdelta[NBATCH];
    __shared__ double sw[16];

    int n_obj = nobj[b];
    {
        float4 g = reinterpret_cast<const float4*>(gt)[b*NMAX + n];
        float x2 = g.x + g.z, y2 = g.y + g.w;
        sbox[tid] = make_float4(g.x, g.y, x2, y2);
        stsa[tid] = thr * ((x2 - g.x) * (y2 - g.y));
    }
    __syncthreads();

    int bi = -1; bool need = false;
    float4 av = make_float4(0.f,0.f,0.f,0.f);
    float ta = 0.f;
    if (n < n_obj) {
        unsigned long long pkv = cells[tid];
        bi = (int)(0x7FFFFFFFu - (unsigned)(pkv & 0xFFFFFFFFull));
        av = reinterpret_cast<const float4*>(anchors)[bi];
        float aar = (av.z - av.x) * (av.w - av.y);
        ta = thr * aar;
        float4 g = sbox[tid];
        float lx = fmaxf(av.x, g.x), ly = fmaxf(av.y, g.y);
        float rx = fminf(av.z, g.z), ry = fminf(av.w, g.w);
        float w  = fmaxf(rx - lx, 0.f), h = fmaxf(ry - ly, 0.f);
        float inter = w * h;
        need = !(inter * t1 > ta + stsa[tid]);   // forced adds a bit only if !pos
    }
    sidx[tid] = need ? bi : -1;
    __syncthreads();

    double delta = 0.0;
    if (need) {
        bool first = true; int extra = 0;
        int base = b * NMAX;
        for (int m = 0; m < NMAX; ++m) {
            if (sidx[base + m] == bi) { if (m < n) first = false; ++extra; }
        }
        if (first) {
            int count = 0;
            for (int m = 0; m < n_obj; ++m) {
                float4 g = sbox[base + m];
                float lx = fmaxf(av.x, g.x), ly = fmaxf(av.y, g.y);
                float rx = fminf(av.z, g.z), ry = fminf(av.w, g.w);
                float w  = fmaxf(rx - lx, 0.f), h = fmaxf(ry - ly, 0.f);
                float inter = w * h;
                count += (inter * t1 > ta + stsa[base + m]) ? 1 : 0;
            }
            float2 c = reinterpret_cast<const float2*>(classes)[(size_t)b * NANCH + bi];
            float po = (count > 0) ? c.y : c.x;
            float oo = 1.f - po;
            float fo = -oo * oo * __logf(po);
            float oldc = fo * (1.f + 10.f * (float)count);
            int cn = count + extra;
            float pn = (cn > 0) ? c.y : c.x;
            float on = 1.f - pn;
            float fn = -on * on * __logf(pn);
            float newc = fn * (1.f + 10.f * (float)cn);
            delta = (double)newc - (double)oldc;
        }
    }
    #pragma unroll
    for (int off = 32; off; off >>= 1) delta += __shfl_xor(delta, off, 64);
    if (n == 0) sdelta[b] = delta;
    __syncthreads();

    // final: 1024 partials map 1:1 to threads, plus 16 deltas
    double v = partials[tid];
    if (tid < NBATCH) v += sdelta[tid];
    #pragma unroll
    for (int off = 32; off; off >>= 1) v += __shfl_xor(v, off, 64);
    if ((tid & 63) == 0) sw[tid >> 6] = v;
    __syncthreads();
    if (tid == 0) {
        double tot = 0.0;
        #pragma unroll
        for (int i = 0; i < 16; ++i) tot += sw[i];
        double cls = tot * (0.01 / 16.0);
        out[0] = (float)cls;   // total = class + coord(0)
        out[1] = (float)cls;
        out[2] = 0.0f;
    }
}

extern "C" void kernel_launch(void* const* d_in, const int* in_sizes, int n_in,
                              void* d_out, int out_size, void* d_ws, size_t ws_size,
                              hipStream_t stream) {
    const float* thr     = (const float*)d_in[0];
    const float* classes = (const float*)d_in[1];
    const float* anchors = (const float*)d_in[2];
    const float* gt      = (const float*)d_in[3];
    const int*   nobj    = (const int*)d_in[4];
    float* out = (float*)d_out;

    unsigned long long* cells = (unsigned long long*)d_ws;
    int*    pairs    = (int*)((char*)d_ws + NBATCH * NMAX * sizeof(unsigned long long));
    double* partials = (double*)((char*)d_ws + NBATCH * NMAX * sizeof(unsigned long long) + 64);

    k_setup<<<1, 64, 0, stream>>>(nobj, cells, pairs);
    k_phase<<<NBLK, THREADS, 0, stream>>>(thr, classes, anchors, gt, nobj, pairs,
                                          cells, partials);
    k_tail<<<1, 1024, 0, stream>>>(thr, classes, anchors, gt, nobj, cells, partials, out);
}